// Round 5
// baseline (375.767 us; speedup 1.0000x reference)
//
#include <hip/hip_runtime.h>

// B=8, T=8, S=500, F_IN=32, F=F_OUT=64, K=3, L=3
#define BB 8
#define TT 8
#define SS 500
#define FIN 32
#define FF 64
#define KP 512          // padded spatial K
#define NBT 64          // B*T
#define KH 576          // 9 * 64 concat-K for the G-mix GEMM
#define WROWS 32768     // padded wcat rows (32000 used)

typedef short bf16x8 __attribute__((ext_vector_type(8)));
typedef float floatx4 __attribute__((ext_vector_type(4)));

__device__ __forceinline__ unsigned f2bf(float x) {
    unsigned u = __builtin_bit_cast(unsigned, x);
    return (u + 0x7FFFu + ((u >> 16) & 1u)) >> 16;   // RNE bf16 in low 16
}
__device__ __forceinline__ float bf2f(unsigned short h) {
    unsigned u = ((unsigned)h) << 16;
    return __builtin_bit_cast(float, u);
}

// ---------------------------------------------------------------------------
// prep1: Asb[512][512] bf16, AsbT[512][512] bf16 (both zero-padded),
//        GcatT[l][f][kk=576] bf16 where kk = m*64+j, m = a*3+b:
//        G_ab = c0_ab H0 + c1_ab H1 + c2_ab H2 (c from s-coefficients),
//        At2[8][8] = At@At fp32.
// ---------------------------------------------------------------------------
__global__ __launch_bounds__(256) void prep1_k(const float* __restrict__ As,
                                               const float* __restrict__ At,
                                               const float* __restrict__ sc,
                                               const float* __restrict__ H,
                                               unsigned short* __restrict__ Asb,
                                               unsigned short* __restrict__ AsbT,
                                               unsigned short* __restrict__ Gct,
                                               float* __restrict__ At2) {
    int idx = blockIdx.x * 256 + threadIdx.x;
    if (idx < 262144) {
        int s = idx >> 9, k = idx & 511;
        Asb[idx] = (s < SS && k < SS) ? (unsigned short)f2bf(As[(size_t)s * SS + k]) : 0;
    } else if (idx < 524288) {
        int r = idx - 262144;
        int j = r >> 9, k = r & 511;
        AsbT[r] = (j < SS && k < SS) ? (unsigned short)f2bf(As[(size_t)k * SS + j]) : 0;
    } else if (idx < 634880) {
        int r = idx - 524288;               // [0, 3*64*576)
        int l = r / 36864;
        int r2 = r - l * 36864;
        int f = r2 / 576;
        int kk = r2 - f * 576;
        int m = kk >> 6, j = kk & 63;
        float s0 = sc[0], s1 = sc[1], s2 = sc[2], s3 = sc[3];
        float c1 = 0.f, c2 = 0.f, base = 0.f;
        switch (m) {
            case 0: c1 = s0; c2 = s0 * s0;
                    base = H[(size_t)(l * 3 + 0) * 4096 + j * 64 + f]; break;
            case 1: c1 = s1; c2 = 2.f * s0 * s1; break;
            case 2: c2 = s1 * s1; break;
            case 3: c1 = s2; c2 = 2.f * s0 * s2; break;
            case 4: c1 = s3; c2 = 2.f * (s0 * s3 + s1 * s2); break;
            case 5: c2 = 2.f * s1 * s3; break;
            case 6: c2 = s2 * s2; break;
            case 7: c2 = 2.f * s2 * s3; break;
            case 8: c2 = s3 * s3; break;
        }
        float val = base
                  + c1 * H[(size_t)(l * 3 + 1) * 4096 + j * 64 + f]
                  + c2 * H[(size_t)(l * 3 + 2) * 4096 + j * 64 + f];
        Gct[(size_t)(l * 64 + f) * 576 + kk] = (unsigned short)f2bf(val);
    } else if (idx < 634944) {
        int r = idx - 634880;              // [0,64)
        int t = r >> 3, u = r & 7;
        float acc = 0.f;
        #pragma unroll
        for (int k = 0; k < 8; ++k) acc += At[t * 8 + k] * At[k * 8 + u];
        At2[r] = acc;
    }
}

// ---------------------------------------------------------------------------
// prep2: Asqb = (As@As) bf16 [512][512], pads auto-zero via zero A/B rows.
// grid (32 row-tiles of 16, 8 col-tiles of 64), 4 waves, nt=1.
// ---------------------------------------------------------------------------
__global__ __launch_bounds__(256) void prep2_k(const unsigned short* __restrict__ Asb,
                                               const unsigned short* __restrict__ AsbT,
                                               unsigned short* __restrict__ Asqb) {
    int tid = threadIdx.x;
    int wave = tid >> 6, lane = tid & 63;
    int l16 = lane & 15, quad = lane >> 4;
    int st = blockIdx.x, ct = blockIdx.y;

    const unsigned short* ap = Asb + (size_t)(st * 16 + l16) * KP + quad * 8;
    const unsigned short* bp = AsbT + (size_t)(ct * 64 + wave * 16 + l16) * KP + quad * 8;
    floatx4 acc = {};
    #pragma unroll 4
    for (int k0 = 0; k0 < KP; k0 += 32)
        acc = __builtin_amdgcn_mfma_f32_16x16x32_bf16(*(const bf16x8*)(ap + k0),
                                                      *(const bf16x8*)(bp + k0), acc, 0, 0, 0);
    int j = ct * 64 + wave * 16 + l16;
    int i0 = st * 16 + quad * 4;
    #pragma unroll
    for (int r = 0; r < 4; ++r)
        Asqb[(size_t)(i0 + r) * KP + j] = (unsigned short)f2bf(acc[r]);
}

// ---------------------------------------------------------------------------
// lin1: xf = x@W1^T + b1 -> xfb bf16 [bt][s][f], xfT bf16 [bt][f][k=s] (k-pad 0)
// grid (8 s-tiles of 64, 64 bt)
// ---------------------------------------------------------------------------
__global__ __launch_bounds__(256) void lin1_k(const float* __restrict__ x,
                                              const float* __restrict__ W1,
                                              const float* __restrict__ b1,
                                              unsigned short* __restrict__ xfb,
                                              unsigned short* __restrict__ xfT) {
    __shared__ float Xs[64][FIN + 1];
    __shared__ float Wl[FIN][FF];
    __shared__ float Ot[64][FF + 1];
    __shared__ float bl[FF];
    int tid = threadIdx.x;
    int bt = blockIdx.y, s0 = blockIdx.x * 64;

    for (int i = tid; i < FIN * FF; i += 256) { int f = i >> 5, j = i & 31; Wl[j][f] = W1[i]; }
    if (tid < FF) bl[tid] = b1[tid];
    const float* xb = x + (size_t)bt * SS * FIN;
    #pragma unroll
    for (int i = 0; i < 8; ++i) {
        int lin = i * 256 + tid; int r = lin >> 5, j = lin & 31;
        int s = s0 + r;
        Xs[r][j] = (s < SS) ? xb[(size_t)s * FIN + j] : 0.f;
    }
    __syncthreads();
    int f = tid & 63, sq = tid >> 6;
    for (int i = 0; i < 16; ++i) {
        int r = sq * 16 + i;
        float acc = bl[f];
        #pragma unroll
        for (int j = 0; j < FIN; ++j) acc += Xs[r][j] * Wl[j][f];
        Ot[r][f] = (s0 + r < SS) ? acc : 0.f;
    }
    __syncthreads();
    // natural bf16 write
    #pragma unroll
    for (int i = 0; i < 16; ++i) {
        int lin = i * 256 + tid; int r = lin >> 6, ff = lin & 63;
        int s = s0 + r;
        if (s < SS) xfb[((size_t)bt * SS + s) * FF + ff] = (unsigned short)f2bf(Ot[r][ff]);
    }
    // transposed bf16 write (pads written as 0)
    {
        int ff = tid >> 2, scol = (tid & 3) * 16;
        unsigned short tmp[16];
        #pragma unroll
        for (int i = 0; i < 16; ++i) tmp[i] = (unsigned short)f2bf(Ot[scol + i][ff]);
        unsigned short* dp = xfT + ((size_t)bt * FF + ff) * KP + s0 + scol;
        #pragma unroll
        for (int q = 0; q < 2; ++q) {
            int4 w;
            w.x = tmp[q*8+0] | (tmp[q*8+1] << 16); w.y = tmp[q*8+2] | (tmp[q*8+3] << 16);
            w.z = tmp[q*8+4] | (tmp[q*8+5] << 16); w.w = tmp[q*8+6] | (tmp[q*8+7] << 16);
            *(int4*)(dp + q * 8) = w;
        }
    }
}

// ---------------------------------------------------------------------------
// smm: u1 = As.xf, u2 = As^2.xf (shared B loads) -> u1b,u2b bf16 [bt][s][f]
// grid (32 s-tiles of 16, 64 bt), 4 waves, nt=1 (wave covers 16 f).
// ---------------------------------------------------------------------------
__global__ __launch_bounds__(256) void smm_k(const unsigned short* __restrict__ Asb,
                                             const unsigned short* __restrict__ Asqb,
                                             const unsigned short* __restrict__ xfT,
                                             unsigned short* __restrict__ u1b,
                                             unsigned short* __restrict__ u2b) {
    int tid = threadIdx.x;
    int wave = tid >> 6, lane = tid & 63;
    int l16 = lane & 15, quad = lane >> 4;
    int st = blockIdx.x, bt = blockIdx.y;

    const unsigned short* ap1 = Asb  + (size_t)(st * 16 + l16) * KP + quad * 8;
    const unsigned short* ap2 = Asqb + (size_t)(st * 16 + l16) * KP + quad * 8;
    const unsigned short* bp  = xfT + ((size_t)bt * FF + wave * 16 + l16) * KP + quad * 8;

    floatx4 a1 = {}, a2 = {};
    #pragma unroll 4
    for (int k0 = 0; k0 < KP; k0 += 32) {
        bf16x8 b = *(const bf16x8*)(bp + k0);
        a1 = __builtin_amdgcn_mfma_f32_16x16x32_bf16(*(const bf16x8*)(ap1 + k0), b, a1, 0, 0, 0);
        a2 = __builtin_amdgcn_mfma_f32_16x16x32_bf16(*(const bf16x8*)(ap2 + k0), b, a2, 0, 0, 0);
    }
    int f = wave * 16 + l16;
    int sb = st * 16 + quad * 4;
    #pragma unroll
    for (int r = 0; r < 4; ++r) {
        int s = sb + r;
        if (s < SS) {
            size_t off = ((size_t)bt * SS + s) * FF + f;
            u1b[off] = (unsigned short)f2bf(a1[r]);
            u2b[off] = (unsigned short)f2bf(a2[r]);
        }
    }
}

// ---------------------------------------------------------------------------
// mix: build wcat[row=(bt*500+s)][m*64+f], m=a*3+b, w_ab = At^a u_b.
// one thread per (b,s,f) = 256000.
// ---------------------------------------------------------------------------
__global__ __launch_bounds__(256) void mix_k(const unsigned short* __restrict__ xfb,
                                             const unsigned short* __restrict__ u1b,
                                             const unsigned short* __restrict__ u2b,
                                             const float* __restrict__ At,
                                             const float* __restrict__ At2,
                                             unsigned short* __restrict__ wcat) {
    __shared__ float Atl[64], At2l[64];
    int tid = threadIdx.x;
    if (tid < 64) { Atl[tid] = At[tid]; At2l[tid] = At2[tid]; }
    __syncthreads();

    int idx = blockIdx.x * 256 + tid;        // B*S*F = 256000
    int f = idx & 63;
    int rest = idx >> 6;
    int s = rest % SS;
    int b = rest / SS;

    float u0[8], u1[8], u2[8];
    #pragma unroll
    for (int t = 0; t < TT; ++t) {
        size_t off = ((size_t)(b * TT + t) * SS + s) * FF + f;
        u0[t] = bf2f(xfb[off]); u1[t] = bf2f(u1b[off]); u2[t] = bf2f(u2b[off]);
    }
    #pragma unroll
    for (int t = 0; t < TT; ++t) {
        float w10 = 0.f, w11 = 0.f, w12 = 0.f, w20 = 0.f, w21 = 0.f, w22 = 0.f;
        #pragma unroll
        for (int tp = 0; tp < TT; ++tp) {
            float a1v = Atl[t * TT + tp], a2v = At2l[t * TT + tp];
            w10 += a1v * u0[tp]; w11 += a1v * u1[tp]; w12 += a1v * u2[tp];
            w20 += a2v * u0[tp]; w21 += a2v * u1[tp]; w22 += a2v * u2[tp];
        }
        unsigned short* wr = wcat + ((size_t)(b * TT + t) * SS + s) * KH + f;
        wr[0 * 64] = (unsigned short)f2bf(u0[t]);
        wr[1 * 64] = (unsigned short)f2bf(u1[t]);
        wr[2 * 64] = (unsigned short)f2bf(u2[t]);
        wr[3 * 64] = (unsigned short)f2bf(w10);
        wr[4 * 64] = (unsigned short)f2bf(w11);
        wr[5 * 64] = (unsigned short)f2bf(w12);
        wr[6 * 64] = (unsigned short)f2bf(w20);
        wr[7 * 64] = (unsigned short)f2bf(w21);
        wr[8 * 64] = (unsigned short)f2bf(w22);
    }
}

// ---------------------------------------------------------------------------
// hmix: xf_next = tanh(wcat @ Gct_l) -> xfb bf16 + xfT bf16 (LDS transpose).
// grid (32 s-tiles of 16, 64 bt), 4 waves, nt=1.
// ---------------------------------------------------------------------------
__global__ __launch_bounds__(256) void hmix_k(const unsigned short* __restrict__ wcat,
                                              const unsigned short* __restrict__ Gct,
                                              unsigned short* __restrict__ xfb,
                                              unsigned short* __restrict__ xfT) {
    __shared__ unsigned short Obf[16][72];
    int tid = threadIdx.x;
    int wave = tid >> 6, lane = tid & 63;
    int l16 = lane & 15, quad = lane >> 4;
    int st = blockIdx.x, bt = blockIdx.y;

    const unsigned short* ap = wcat + ((size_t)bt * SS + st * 16 + l16) * KH + quad * 8;
    const unsigned short* bp = Gct + (size_t)(wave * 16 + l16) * KH + quad * 8;

    floatx4 acc = {};
    #pragma unroll 6
    for (int k0 = 0; k0 < KH; k0 += 32)
        acc = __builtin_amdgcn_mfma_f32_16x16x32_bf16(*(const bf16x8*)(ap + k0),
                                                      *(const bf16x8*)(bp + k0), acc, 0, 0, 0);
    int f = wave * 16 + l16;
    #pragma unroll
    for (int r = 0; r < 4; ++r) {
        int sl = quad * 4 + r;
        int s = st * 16 + sl;
        float o = tanhf(acc[r]);
        unsigned short ob = (unsigned short)f2bf(o);
        if (s < SS) xfb[((size_t)bt * SS + s) * FF + f] = ob;
        Obf[sl][f] = ob;       // finite garbage for s>=SS; zeroed-A makes it inert
    }
    __syncthreads();
    // transposed write: thread (f = tid&63, g = tid>>6) packs 4 s
    int ff = tid & 63, g = tid >> 6;
    unsigned short t0 = Obf[g * 4 + 0][ff], t1 = Obf[g * 4 + 1][ff];
    unsigned short t2 = Obf[g * 4 + 2][ff], t3 = Obf[g * 4 + 3][ff];
    int2 w;
    w.x = t0 | (t1 << 16); w.y = t2 | (t3 << 16);
    *(int2*)(xfT + ((size_t)bt * FF + ff) * KP + st * 16 + g * 4) = w;
}

// ---------------------------------------------------------------------------
// zredlin2: out[b,s,f] = b2[f]*sum(m) + sum_j (sum_t m[t] xf[b,t,s,j]) * W2[f,j]
// grid (32 s-tiles of 16, 8 b)
// ---------------------------------------------------------------------------
__global__ __launch_bounds__(256) void zredlin2_k(const unsigned short* __restrict__ xfb,
                                                  const float* __restrict__ W2,
                                                  const float* __restrict__ b2,
                                                  const float* __restrict__ merge,
                                                  float* __restrict__ out) {
    __shared__ float Wl[FF][FF + 1];
    __shared__ float zt[16][FF + 1];
    __shared__ float ml[TT];
    int tid = threadIdx.x;
    int b = blockIdx.y, s0 = blockIdx.x * 16;

    for (int i = tid; i < FF * FF; i += 256) { int f = i >> 6, j = i & 63; Wl[j][f] = W2[i]; }
    if (tid < TT) ml[tid] = merge[tid];
    __syncthreads();

    float m[TT];
    #pragma unroll
    for (int t = 0; t < TT; ++t) m[t] = ml[t];
    float msum = 0.f;
    #pragma unroll
    for (int t = 0; t < TT; ++t) msum += m[t];

    #pragma unroll
    for (int p = 0; p < 4; ++p) {
        int lin = p * 256 + tid;
        int sl = lin >> 6, f = lin & 63;
        int s = s0 + sl;
        float acc = 0.f;
        if (s < SS) {
            #pragma unroll
            for (int t = 0; t < TT; ++t)
                acc += m[t] * bf2f(xfb[((size_t)(b * TT + t) * SS + s) * FF + f]);
        }
        zt[sl][f] = acc;
    }
    __syncthreads();

    int f = tid & 63, sq = tid >> 6;
    #pragma unroll
    for (int i = 0; i < 4; ++i) {
        int sl = sq * 4 + i;
        int s = s0 + sl;
        if (s < SS) {
            float acc = b2[f] * msum;
            #pragma unroll
            for (int j = 0; j < FF; ++j) acc += zt[sl][j] * Wl[j][f];
            out[((size_t)b * SS + s) * FF + f] = acc;
        }
    }
}

// ---------------------------------------------------------------------------
extern "C" void kernel_launch(void* const* d_in, const int* in_sizes, int n_in,
                              void* d_out, int out_size, void* d_ws, size_t ws_size,
                              hipStream_t stream) {
    const float* x     = (const float*)d_in[0];
    const float* At    = (const float*)d_in[1];
    const float* As    = (const float*)d_in[2];
    const float* sc    = (const float*)d_in[3];
    const float* H     = (const float*)d_in[4];
    const float* W1    = (const float*)d_in[5];
    const float* b1    = (const float*)d_in[6];
    const float* W2    = (const float*)d_in[7];
    const float* b2    = (const float*)d_in[8];
    const float* merge = (const float*)d_in[9];
    float* out = (float*)d_out;

    char* ws = (char*)d_ws;
    unsigned short* Asb  = (unsigned short*)(ws + 0);         // 524288
    unsigned short* AsbT = (unsigned short*)(ws + 524288);    // 524288
    unsigned short* Asqb = (unsigned short*)(ws + 1048576);   // 524288
    unsigned short* Gct  = (unsigned short*)(ws + 1572864);   // 221184
    float*          At2  = (float*)(ws + 1794048);            // 256
    unsigned short* xfb  = (unsigned short*)(ws + 2097152);   // 4096000
    unsigned short* xfT  = (unsigned short*)(ws + 6291456);   // 4194304
    unsigned short* u1b  = (unsigned short*)(ws + 10485760);  // 4096000
    unsigned short* u2b  = (unsigned short*)(ws + 14680064);  // 4096000
    unsigned short* wcat = (unsigned short*)(ws + 18874368);  // 32768*576*2 = 37748736

    prep1_k<<<2481, 256, 0, stream>>>(As, At, sc, H, Asb, AsbT, Gct, At2);
    prep2_k<<<dim3(32, 8), 256, 0, stream>>>(Asb, AsbT, Asqb);
    lin1_k<<<dim3(8, NBT), 256, 0, stream>>>(x, W1, b1, xfb, xfT);

    for (int l = 0; l < 3; ++l) {
        smm_k<<<dim3(32, NBT), 256, 0, stream>>>(Asb, Asqb, xfT, u1b, u2b);
        mix_k<<<1000, 256, 0, stream>>>(xfb, u1b, u2b, At, At2, wcat);
        hmix_k<<<dim3(32, NBT), 256, 0, stream>>>(wcat, Gct + (size_t)l * FF * KH,
                                                  xfb, xfT);
    }
    zredlin2_k<<<dim3(32, 8), 256, 0, stream>>>(xfb, W2, b2, merge, out);
}

// Round 6
// 239.198 us; speedup vs baseline: 1.5709x; 1.5709x over previous
//
#include <hip/hip_runtime.h>

// B=8, T=8, S=500 (padded 512), F_IN=32, F=F_OUT=64, K=3, L=3
#define BB 8
#define TT 8
#define SS 500
#define SP 512
#define FIN 32
#define FF 64
#define NBT 64
#define KT 1536        // 24 * 64 : tmix GEMM K
#define LROW 72        // LDS row stride in shorts (144 B, 16B-aligned, bank-shift 4)

typedef short bf16x8 __attribute__((ext_vector_type(8)));
typedef float floatx4 __attribute__((ext_vector_type(4)));

__device__ __forceinline__ unsigned f2bf(float x) {
    unsigned u = __builtin_bit_cast(unsigned, x);
    return (u + 0x7FFFu + ((u >> 16) & 1u)) >> 16;   // RNE bf16 in low 16
}
__device__ __forceinline__ float bf2f(unsigned short h) {
    unsigned u = ((unsigned)h) << 16;
    return __builtin_bit_cast(float, u);
}

// ---------------------------------------------------------------------------
// prep1: Asb[512][512] bf16, AsbT[512][512] bf16 (zero-padded), At2 = At@At
// ---------------------------------------------------------------------------
__global__ __launch_bounds__(256) void prep1_k(const float* __restrict__ As,
                                               const float* __restrict__ At,
                                               unsigned short* __restrict__ Asb,
                                               unsigned short* __restrict__ AsbT,
                                               float* __restrict__ At2) {
    int idx = blockIdx.x * 256 + threadIdx.x;
    if (idx < 262144) {
        int s = idx >> 9, k = idx & 511;
        Asb[idx] = (s < SS && k < SS) ? (unsigned short)f2bf(As[(size_t)s * SS + k]) : 0;
    } else if (idx < 524288) {
        int r = idx - 262144;
        int j = r >> 9, k = r & 511;
        AsbT[r] = (j < SS && k < SS) ? (unsigned short)f2bf(As[(size_t)k * SS + j]) : 0;
    } else if (idx < 524352) {
        int r = idx - 524288;
        int t = r >> 3, u = r & 7;
        float acc = 0.f;
        #pragma unroll
        for (int k = 0; k < 8; ++k) acc += At[t * 8 + k] * At[k * 8 + u];
        At2[r] = acc;
    }
}

// ---------------------------------------------------------------------------
// prep2: Asqb = (As@As) bf16 [512][512]
// ---------------------------------------------------------------------------
__global__ __launch_bounds__(256) void prep2_k(const unsigned short* __restrict__ Asb,
                                               const unsigned short* __restrict__ AsbT,
                                               unsigned short* __restrict__ Asqb) {
    int tid = threadIdx.x;
    int wave = tid >> 6, lane = tid & 63;
    int l16 = lane & 15, quad = lane >> 4;
    int st = blockIdx.x, ct = blockIdx.y;

    const unsigned short* ap = Asb + (size_t)(st * 16 + l16) * SP + quad * 8;
    const unsigned short* bp = AsbT + (size_t)(ct * 64 + wave * 16 + l16) * SP + quad * 8;
    floatx4 acc = {};
    #pragma unroll 4
    for (int k0 = 0; k0 < SP; k0 += 32)
        acc = __builtin_amdgcn_mfma_f32_16x16x32_bf16(*(const bf16x8*)(ap + k0),
                                                      *(const bf16x8*)(bp + k0), acc, 0, 0, 0);
    int j = ct * 64 + wave * 16 + l16;
    int i0 = st * 16 + quad * 4;
    #pragma unroll
    for (int r = 0; r < 4; ++r)
        Asqb[(size_t)(i0 + r) * SP + j] = (unsigned short)f2bf(acc[r]);
}

// ---------------------------------------------------------------------------
// prep3: GbigT[l][t][f][k=1536] bf16, k = (t'*3+b')*64 + j.
// Gbig = sum_a At^a[t,t'] * G_{a,b'}[j][f];  G_ab = c0 H0 + c1 H1 + c2 H2.
// ---------------------------------------------------------------------------
__device__ __forceinline__ void ctab(int m, float s0, float s1, float s2, float s3,
                                     float& c0, float& c1, float& c2) {
    c0 = 0.f; c1 = 0.f; c2 = 0.f;
    switch (m) {
        case 0: c0 = 1.f; c1 = s0; c2 = s0 * s0; break;
        case 1: c1 = s1; c2 = 2.f * s0 * s1; break;
        case 2: c2 = s1 * s1; break;
        case 3: c1 = s2; c2 = 2.f * s0 * s2; break;
        case 4: c1 = s3; c2 = 2.f * (s0 * s3 + s1 * s2); break;
        case 5: c2 = 2.f * s1 * s3; break;
        case 6: c2 = s2 * s2; break;
        case 7: c2 = 2.f * s2 * s3; break;
        case 8: c2 = s3 * s3; break;
    }
}

__global__ __launch_bounds__(256) void prep3_k(const float* __restrict__ At,
                                               const float* __restrict__ At2,
                                               const float* __restrict__ sc,
                                               const float* __restrict__ H,
                                               unsigned short* __restrict__ GbigT) {
    int idx = blockIdx.x * 256 + threadIdx.x;     // 3*8*64*1536 = 2359296
    if (idx >= 3 * 8 * 64 * KT) return;
    int l = idx / (8 * 64 * KT);
    int r = idx - l * (8 * 64 * KT);
    int t = r / (64 * KT);
    int r2 = r - t * (64 * KT);
    int f = r2 / KT;
    int k = r2 - f * KT;
    int seg = k >> 6, j = k & 63;
    int tp = seg / 3, bp = seg - tp * 3;

    float s0 = sc[0], s1 = sc[1], s2 = sc[2], s3 = sc[3];
    float w0 = (t == tp) ? 1.f : 0.f;
    float w1 = At[t * 8 + tp];
    float w2 = At2[t * 8 + tp];

    float a0, a1, a2, b0, b1, b2, d0, d1, d2;
    ctab(0 * 3 + bp, s0, s1, s2, s3, a0, a1, a2);
    ctab(1 * 3 + bp, s0, s1, s2, s3, b0, b1, b2);
    ctab(2 * 3 + bp, s0, s1, s2, s3, d0, d1, d2);
    float k0c = w0 * a0 + w1 * b0 + w2 * d0;
    float k1c = w0 * a1 + w1 * b1 + w2 * d1;
    float k2c = w0 * a2 + w1 * b2 + w2 * d2;

    float val = k0c * H[((size_t)(l * 3 + 0) * 64 + j) * 64 + f]
              + k1c * H[((size_t)(l * 3 + 1) * 64 + j) * 64 + f]
              + k2c * H[((size_t)(l * 3 + 2) * 64 + j) * 64 + f];
    GbigT[idx] = (unsigned short)f2bf(val);
}

// ---------------------------------------------------------------------------
// lin1: xf = x@W1^T + b1 -> xfb bf16 [bt][512][f] (pad 0), xfT bf16 [bt][f][512]
// grid (8 s-tiles of 64, 64 bt)
// ---------------------------------------------------------------------------
__global__ __launch_bounds__(256) void lin1_k(const float* __restrict__ x,
                                              const float* __restrict__ W1,
                                              const float* __restrict__ b1,
                                              unsigned short* __restrict__ xfb,
                                              unsigned short* __restrict__ xfT) {
    __shared__ float Xs[64][FIN + 1];
    __shared__ float Wl[FIN][FF];
    __shared__ float Ot[64][FF + 1];
    __shared__ float bl[FF];
    int tid = threadIdx.x;
    int bt = blockIdx.y, s0 = blockIdx.x * 64;

    for (int i = tid; i < FIN * FF; i += 256) { int f = i >> 5, j = i & 31; Wl[j][f] = W1[i]; }
    if (tid < FF) bl[tid] = b1[tid];
    const float* xb = x + (size_t)bt * SS * FIN;
    #pragma unroll
    for (int i = 0; i < 8; ++i) {
        int lin = i * 256 + tid; int r = lin >> 5, j = lin & 31;
        int s = s0 + r;
        Xs[r][j] = (s < SS) ? xb[(size_t)s * FIN + j] : 0.f;
    }
    __syncthreads();
    int f = tid & 63, sq = tid >> 6;
    for (int i = 0; i < 16; ++i) {
        int r = sq * 16 + i;
        float acc = bl[f];
        #pragma unroll
        for (int j = 0; j < FIN; ++j) acc += Xs[r][j] * Wl[j][f];
        Ot[r][f] = (s0 + r < SS) ? acc : 0.f;
    }
    __syncthreads();
    // natural bf16 write (incl. zero pads)
    #pragma unroll
    for (int i = 0; i < 16; ++i) {
        int lin = i * 256 + tid; int r = lin >> 6, ff = lin & 63;
        xfb[((size_t)bt * SP + s0 + r) * FF + ff] = (unsigned short)f2bf(Ot[r][ff]);
    }
    // transposed bf16 write
    {
        int ff = tid >> 2, scol = (tid & 3) * 16;
        unsigned short tmp[16];
        #pragma unroll
        for (int i = 0; i < 16; ++i) tmp[i] = (unsigned short)f2bf(Ot[scol + i][ff]);
        unsigned short* dp = xfT + ((size_t)bt * FF + ff) * SP + s0 + scol;
        #pragma unroll
        for (int q = 0; q < 2; ++q) {
            int4 w;
            w.x = tmp[q*8+0] | (tmp[q*8+1] << 16); w.y = tmp[q*8+2] | (tmp[q*8+3] << 16);
            w.z = tmp[q*8+4] | (tmp[q*8+5] << 16); w.w = tmp[q*8+6] | (tmp[q*8+7] << 16);
            *(int4*)(dp + q * 8) = w;
        }
    }
}

// ---------------------------------------------------------------------------
// smm: dual LDS-tiled GEMM. u1 = As.xf, u2 = As^2.xf.
// M=512(s) x N=4096(bt*64+f) x K=512. BM=BN=BK=64. grid (8 m-tiles, 64 bt).
// Wave w: m-rows [w*16,w*16+16), all 64 n. Outputs bf16 natural [bt][512][64].
// ---------------------------------------------------------------------------
__global__ __launch_bounds__(256) void smm_k(const unsigned short* __restrict__ Asb,
                                             const unsigned short* __restrict__ Asqb,
                                             const unsigned short* __restrict__ xfT,
                                             unsigned short* __restrict__ u1b,
                                             unsigned short* __restrict__ u2b) {
    __shared__ unsigned short A1[64 * LROW];
    __shared__ unsigned short A2[64 * LROW];
    __shared__ unsigned short Bt[64 * LROW];

    int tid = threadIdx.x;
    int wave = tid >> 6, lane = tid & 63;
    int l16 = lane & 15, quad = lane >> 4;
    int m0 = blockIdx.x * 64, bt = blockIdx.y;

    const unsigned short* a1g = Asb + (size_t)m0 * SP;
    const unsigned short* a2g = Asqb + (size_t)m0 * SP;
    const unsigned short* bg  = xfT + (size_t)bt * FF * SP;

    floatx4 acc1[4] = {}, acc2[4] = {};

    for (int k0 = 0; k0 < SP; k0 += 64) {
        __syncthreads();
        #pragma unroll
        for (int it = 0; it < 2; ++it) {
            int idx = it * 256 + tid;
            int row = idx >> 3, c = idx & 7;
            int4 v1 = *(const int4*)(a1g + (size_t)row * SP + k0 + c * 8);
            int4 v2 = *(const int4*)(a2g + (size_t)row * SP + k0 + c * 8);
            int4 vb = *(const int4*)(bg  + (size_t)row * SP + k0 + c * 8);
            *(int4*)&A1[row * LROW + c * 8] = v1;
            *(int4*)&A2[row * LROW + c * 8] = v2;
            *(int4*)&Bt[row * LROW + c * 8] = vb;
        }
        __syncthreads();
        #pragma unroll
        for (int ks = 0; ks < 2; ++ks) {
            bf16x8 af1 = *(const bf16x8*)&A1[(wave * 16 + l16) * LROW + ks * 32 + quad * 8];
            bf16x8 af2 = *(const bf16x8*)&A2[(wave * 16 + l16) * LROW + ks * 32 + quad * 8];
            #pragma unroll
            for (int nt = 0; nt < 4; ++nt) {
                bf16x8 bf = *(const bf16x8*)&Bt[(nt * 16 + l16) * LROW + ks * 32 + quad * 8];
                acc1[nt] = __builtin_amdgcn_mfma_f32_16x16x32_bf16(af1, bf, acc1[nt], 0, 0, 0);
                acc2[nt] = __builtin_amdgcn_mfma_f32_16x16x32_bf16(af2, bf, acc2[nt], 0, 0, 0);
            }
        }
    }

    // epilogue: repack via wave-private LDS rows (A1/A2 rows [wave*16, +16))
    __syncthreads();
    #pragma unroll
    for (int nt = 0; nt < 4; ++nt)
        #pragma unroll
        for (int r = 0; r < 4; ++r) {
            A1[(wave * 16 + quad * 4 + r) * LROW + nt * 16 + l16] = (unsigned short)f2bf(acc1[nt][r]);
            A2[(wave * 16 + quad * 4 + r) * LROW + nt * 16 + l16] = (unsigned short)f2bf(acc2[nt][r]);
        }
    __syncthreads();
    int row = wave * 16 + (lane >> 2);
    int c2 = (lane & 3) * 2;
    #pragma unroll
    for (int q = 0; q < 2; ++q) {
        int c = c2 + q;
        int4 v1 = *(const int4*)&A1[row * LROW + c * 8];
        int4 v2 = *(const int4*)&A2[row * LROW + c * 8];
        size_t off = ((size_t)bt * SP + m0 + row) * FF + c * 8;
        *(int4*)(u1b + off) = v1;
        *(int4*)(u2b + off) = v2;
    }
}

// ---------------------------------------------------------------------------
// tmix: out[b,t,s,:] = tanh( sum_{t',b'} u_{b'}[b,t',s,:] @ Gbig[t][(t',b')] )
// M=64(s) x N=64(f) x K=1536, BK=64 (one (t',b') segment per step).
// grid (8 s-tiles, 8 b, 8 t). Writes xfb_next + xfT_next (bf16).
// ---------------------------------------------------------------------------
__global__ __launch_bounds__(256) void tmix_k(const unsigned short* __restrict__ xfb,
                                              const unsigned short* __restrict__ u1b,
                                              const unsigned short* __restrict__ u2b,
                                              const unsigned short* __restrict__ Gbig_l,
                                              unsigned short* __restrict__ xfb_out,
                                              unsigned short* __restrict__ xfT_out) {
    __shared__ unsigned short At_[64 * LROW];
    __shared__ unsigned short Bt_[64 * LROW];

    int tid = threadIdx.x;
    int wave = tid >> 6, lane = tid & 63;
    int l16 = lane & 15, quad = lane >> 4;
    int s0 = blockIdx.x * 64, b = blockIdx.y, t = blockIdx.z;

    const unsigned short* bufs[3] = { xfb, u1b, u2b };
    const unsigned short* bg = Gbig_l + (size_t)t * FF * KT;

    floatx4 acc[4] = {};

    for (int kk = 0; kk < 24; ++kk) {
        int tp = kk / 3, bp = kk - tp * 3;
        const unsigned short* ag = bufs[bp] + ((size_t)(b * 8 + tp) * SP + s0) * FF;
        __syncthreads();
        #pragma unroll
        for (int it = 0; it < 2; ++it) {
            int idx = it * 256 + tid;
            int row = idx >> 3, c = idx & 7;
            int4 va = *(const int4*)(ag + (size_t)row * FF + c * 8);
            int4 vb = *(const int4*)(bg + (size_t)row * KT + kk * 64 + c * 8);
            *(int4*)&At_[row * LROW + c * 8] = va;
            *(int4*)&Bt_[row * LROW + c * 8] = vb;
        }
        __syncthreads();
        #pragma unroll
        for (int ks = 0; ks < 2; ++ks) {
            bf16x8 af = *(const bf16x8*)&At_[(wave * 16 + l16) * LROW + ks * 32 + quad * 8];
            #pragma unroll
            for (int nt = 0; nt < 4; ++nt) {
                bf16x8 bf = *(const bf16x8*)&Bt_[(nt * 16 + l16) * LROW + ks * 32 + quad * 8];
                acc[nt] = __builtin_amdgcn_mfma_f32_16x16x32_bf16(af, bf, acc[nt], 0, 0, 0);
            }
        }
    }

    // tanh
    #pragma unroll
    for (int nt = 0; nt < 4; ++nt)
        #pragma unroll
        for (int r = 0; r < 4; ++r) acc[nt][r] = tanhf(acc[nt][r]);

    int bt = b * 8 + t;

    // natural repack (wave-private A rows) + store
    __syncthreads();
    #pragma unroll
    for (int nt = 0; nt < 4; ++nt)
        #pragma unroll
        for (int r = 0; r < 4; ++r)
            At_[(wave * 16 + quad * 4 + r) * LROW + nt * 16 + l16] = (unsigned short)f2bf(acc[nt][r]);
    __syncthreads();
    {
        int row = wave * 16 + (lane >> 2);
        int c2 = (lane & 3) * 2;
        #pragma unroll
        for (int q = 0; q < 2; ++q) {
            int c = c2 + q;
            int4 v = *(const int4*)&At_[row * LROW + c * 8];
            *(int4*)(xfb_out + ((size_t)bt * SP + s0 + row) * FF + c * 8) = v;
        }
    }

    // transposed repack (block-wide into Bt_) + store
    __syncthreads();
    #pragma unroll
    for (int nt = 0; nt < 4; ++nt)
        #pragma unroll
        for (int r = 0; r < 4; ++r)
            Bt_[(nt * 16 + l16) * LROW + wave * 16 + quad * 4 + r] = (unsigned short)f2bf(acc[nt][r]);
    __syncthreads();
    #pragma unroll
    for (int it = 0; it < 2; ++it) {
        int idx = it * 256 + tid;
        int frow = idx >> 3, c = idx & 7;
        int4 v = *(const int4*)&Bt_[frow * LROW + c * 8];
        *(int4*)(xfT_out + ((size_t)bt * FF + frow) * SP + s0 + c * 8) = v;
    }
}

// ---------------------------------------------------------------------------
// zredlin2: out[b,s,f] = b2[f]*sum(m) + sum_j (sum_t m[t] xf[b,t,s,j]) * W2[f,j]
// ---------------------------------------------------------------------------
__global__ __launch_bounds__(256) void zredlin2_k(const unsigned short* __restrict__ xfb,
                                                  const float* __restrict__ W2,
                                                  const float* __restrict__ b2,
                                                  const float* __restrict__ merge,
                                                  float* __restrict__ out) {
    __shared__ float Wl[FF][FF + 1];
    __shared__ float zt[16][FF + 1];
    __shared__ float ml[TT];
    int tid = threadIdx.x;
    int b = blockIdx.y, s0 = blockIdx.x * 16;

    for (int i = tid; i < FF * FF; i += 256) { int f = i >> 6, j = i & 63; Wl[j][f] = W2[i]; }
    if (tid < TT) ml[tid] = merge[tid];
    __syncthreads();

    float m[TT];
    #pragma unroll
    for (int t = 0; t < TT; ++t) m[t] = ml[t];
    float msum = 0.f;
    #pragma unroll
    for (int t = 0; t < TT; ++t) msum += m[t];

    #pragma unroll
    for (int p = 0; p < 4; ++p) {
        int lin = p * 256 + tid;
        int sl = lin >> 6, f = lin & 63;
        int s = s0 + sl;
        float acc = 0.f;
        if (s < SS) {
            #pragma unroll
            for (int t = 0; t < TT; ++t)
                acc += m[t] * bf2f(xfb[((size_t)(b * TT + t) * SP + s) * FF + f]);
        }
        zt[sl][f] = acc;
    }
    __syncthreads();

    int f = tid & 63, sq = tid >> 6;
    #pragma unroll
    for (int i = 0; i < 4; ++i) {
        int sl = sq * 4 + i;
        int s = s0 + sl;
        if (s < SS) {
            float acc = b2[f] * msum;
            #pragma unroll
            for (int j = 0; j < FF; ++j) acc += zt[sl][j] * Wl[j][f];
            out[((size_t)b * SS + s) * FF + f] = acc;
        }
    }
}

// ---------------------------------------------------------------------------
extern "C" void kernel_launch(void* const* d_in, const int* in_sizes, int n_in,
                              void* d_out, int out_size, void* d_ws, size_t ws_size,
                              hipStream_t stream) {
    const float* x     = (const float*)d_in[0];
    const float* At    = (const float*)d_in[1];
    const float* As    = (const float*)d_in[2];
    const float* sc    = (const float*)d_in[3];
    const float* H     = (const float*)d_in[4];
    const float* W1    = (const float*)d_in[5];
    const float* b1    = (const float*)d_in[6];
    const float* W2    = (const float*)d_in[7];
    const float* b2    = (const float*)d_in[8];
    const float* merge = (const float*)d_in[9];
    float* out = (float*)d_out;

    char* ws = (char*)d_ws;
    unsigned short* Asb   = (unsigned short*)(ws + 0);          // 524288
    unsigned short* AsbT  = (unsigned short*)(ws + 524288);     // 524288
    unsigned short* Asqb  = (unsigned short*)(ws + 1048576);    // 524288
    float*          At2   = (float*)(ws + 1572864);             // 256
    unsigned short* GbigT = (unsigned short*)(ws + 2097152);    // 4718592
    unsigned short* xfb0  = (unsigned short*)(ws + 6815744);    // 4194304
    unsigned short* xfT0  = (unsigned short*)(ws + 11010048);   // 4194304
    unsigned short* xfb1  = (unsigned short*)(ws + 15204352);   // 4194304
    unsigned short* xfT1  = (unsigned short*)(ws + 19398656);   // 4194304
    unsigned short* u1b   = (unsigned short*)(ws + 23592960);   // 4194304
    unsigned short* u2b   = (unsigned short*)(ws + 27787264);   // 4194304

    prep1_k<<<2049, 256, 0, stream>>>(As, At, Asb, AsbT, At2);
    prep2_k<<<dim3(32, 8), 256, 0, stream>>>(Asb, AsbT, Asqb);
    prep3_k<<<9216, 256, 0, stream>>>(At, At2, sc, H, GbigT);
    lin1_k<<<dim3(8, NBT), 256, 0, stream>>>(x, W1, b1, xfb0, xfT0);

    unsigned short* xfb_cur = xfb0; unsigned short* xfT_cur = xfT0;
    unsigned short* xfb_nxt = xfb1; unsigned short* xfT_nxt = xfT1;
    for (int l = 0; l < 3; ++l) {
        smm_k<<<dim3(8, NBT), 256, 0, stream>>>(Asb, Asqb, xfT_cur, u1b, u2b);
        tmix_k<<<dim3(8, 8, 8), 256, 0, stream>>>(xfb_cur, u1b, u2b,
                                                  GbigT + (size_t)l * 8 * FF * KT,
                                                  xfb_nxt, xfT_nxt);
        unsigned short* tb = xfb_cur; xfb_cur = xfb_nxt; xfb_nxt = tb;
        unsigned short* tt = xfT_cur; xfT_cur = xfT_nxt; xfT_nxt = tt;
    }
    zredlin2_k<<<dim3(32, 8), 256, 0, stream>>>(xfb_cur, W2, b2, merge, out);
}

// Round 8
// 209.721 us; speedup vs baseline: 1.7918x; 1.1406x over previous
//
#include <hip/hip_runtime.h>

// B=8, T=8, S=500 (padded 512), F_IN=32, F=F_OUT=64, K=3, L=3
#define BB 8
#define TT 8
#define SS 500
#define SP 512
#define FIN 32
#define FF 64
#define NBT 64
#define KT 1536        // 24 * 64 : tmix GEMM K  (k = t'*192 + b'*64 + j)
#define LROW 72        // LDS row stride in shorts (144 B, 16B-aligned)

typedef short bf16x8 __attribute__((ext_vector_type(8)));
typedef float floatx4 __attribute__((ext_vector_type(4)));

__device__ __forceinline__ unsigned f2bf(float x) {
    unsigned u = __builtin_bit_cast(unsigned, x);
    return (u + 0x7FFFu + ((u >> 16) & 1u)) >> 16;   // RNE bf16 in low 16
}
__device__ __forceinline__ float bf2f(unsigned short h) {
    unsigned u = ((unsigned)h) << 16;
    return __builtin_bit_cast(float, u);
}

__device__ __forceinline__ void ctab(int m, float s0, float s1, float s2, float s3,
                                     float& c0, float& c1, float& c2) {
    c0 = 0.f; c1 = 0.f; c2 = 0.f;
    switch (m) {
        case 0: c0 = 1.f; c1 = s0; c2 = s0 * s0; break;
        case 1: c1 = s1; c2 = 2.f * s0 * s1; break;
        case 2: c2 = s1 * s1; break;
        case 3: c1 = s2; c2 = 2.f * s0 * s2; break;
        case 4: c1 = s3; c2 = 2.f * (s0 * s3 + s1 * s2); break;
        case 5: c2 = 2.f * s1 * s3; break;
        case 6: c2 = s2 * s2; break;
        case 7: c2 = 2.f * s2 * s3; break;
        case 8: c2 = s3 * s3; break;
    }
}

// ---------------------------------------------------------------------------
// setup_k: blocks [0,512): lin1 (xf = x@W1^T+b1 -> xfT0 + Abig0 slot0)
//          blocks [512,...): Asb / AsbT bf16 (zero-padded) + GbigT
// GbigT[l][t][f][k=1536], k = (t'*3+b')*64+j:
//   Gbig = sum_a At^a[t,t'] * (c_ab(s) H-combination)[j][f], At2 inline.
// ---------------------------------------------------------------------------
__global__ __launch_bounds__(256) void setup_k(const float* __restrict__ x,
                                               const float* __restrict__ W1,
                                               const float* __restrict__ b1,
                                               const float* __restrict__ As,
                                               const float* __restrict__ At,
                                               const float* __restrict__ sc,
                                               const float* __restrict__ H,
                                               unsigned short* __restrict__ Asb,
                                               unsigned short* __restrict__ AsbT,
                                               unsigned short* __restrict__ GbigT,
                                               unsigned short* __restrict__ xfT,
                                               unsigned short* __restrict__ Abig0) {
    int tid = threadIdx.x;
    if (blockIdx.x < 512) {
        // ---- lin1 path
        __shared__ float Xs[64][FIN + 1];
        __shared__ float Wl[FIN][FF];
        __shared__ float Ot[64][FF + 1];
        __shared__ float bl[FF];
        int bt = blockIdx.x >> 3, s0 = (blockIdx.x & 7) * 64;
        int b = bt >> 3, t = bt & 7;

        for (int i = tid; i < FIN * FF; i += 256) { int f = i >> 5, j = i & 31; Wl[j][f] = W1[i]; }
        if (tid < FF) bl[tid] = b1[tid];
        const float* xb = x + (size_t)bt * SS * FIN;
        #pragma unroll
        for (int i = 0; i < 8; ++i) {
            int lin = i * 256 + tid; int r = lin >> 5, j = lin & 31;
            int s = s0 + r;
            Xs[r][j] = (s < SS) ? xb[(size_t)s * FIN + j] : 0.f;
        }
        __syncthreads();
        int f = tid & 63, sq = tid >> 6;
        for (int i = 0; i < 16; ++i) {
            int r = sq * 16 + i;
            float acc = bl[f];
            #pragma unroll
            for (int j = 0; j < FIN; ++j) acc += Xs[r][j] * Wl[j][f];
            Ot[r][f] = (s0 + r < SS) ? acc : 0.f;
        }
        __syncthreads();
        // Abig0 slot0 write (row-major)
        #pragma unroll
        for (int it = 0; it < 2; ++it) {
            int idx = it * 256 + tid;
            int row = idx >> 3, c = idx & 7;
            int4 w;
            unsigned short tmp[8];
            #pragma unroll
            for (int q = 0; q < 8; ++q) tmp[q] = (unsigned short)f2bf(Ot[row][c * 8 + q]);
            w.x = tmp[0] | (tmp[1] << 16); w.y = tmp[2] | (tmp[3] << 16);
            w.z = tmp[4] | (tmp[5] << 16); w.w = tmp[6] | (tmp[7] << 16);
            *(int4*)(Abig0 + (size_t)(b * SP + s0 + row) * KT + t * 192 + c * 8) = w;
        }
        // transposed write
        {
            int ff = tid >> 2, scol = (tid & 3) * 16;
            unsigned short tmp[16];
            #pragma unroll
            for (int i = 0; i < 16; ++i) tmp[i] = (unsigned short)f2bf(Ot[scol + i][ff]);
            unsigned short* dp = xfT + ((size_t)bt * FF + ff) * SP + s0 + scol;
            #pragma unroll
            for (int q = 0; q < 2; ++q) {
                int4 w;
                w.x = tmp[q*8+0] | (tmp[q*8+1] << 16); w.y = tmp[q*8+2] | (tmp[q*8+3] << 16);
                w.z = tmp[q*8+4] | (tmp[q*8+5] << 16); w.w = tmp[q*8+6] | (tmp[q*8+7] << 16);
                *(int4*)(dp + q * 8) = w;
            }
        }
        return;
    }
    // ---- prep path
    int idx = (blockIdx.x - 512) * 256 + tid;
    if (idx < 262144) {
        int s = idx >> 9, k = idx & 511;
        Asb[idx] = (s < SS && k < SS) ? (unsigned short)f2bf(As[(size_t)s * SS + k]) : 0;
    } else if (idx < 524288) {
        int r = idx - 262144;
        int j = r >> 9, k = r & 511;
        AsbT[r] = (j < SS && k < SS) ? (unsigned short)f2bf(As[(size_t)k * SS + j]) : 0;
    } else {
        int r = idx - 524288;                 // [0, 3*8*64*1536)
        if (r < 2359296) {
            int l = r / 786432;
            int r2 = r - l * 786432;
            int t = r2 / 98304;
            int r3 = r2 - t * 98304;
            int f = r3 / 1536;
            int k = r3 - f * 1536;            // FIX: 1536 not pow2 — must subtract, not AND
            int seg = k >> 6, j = k & 63;
            int tp = seg / 3, bp = seg - tp * 3;

            float s0 = sc[0], s1 = sc[1], s2 = sc[2], s3 = sc[3];
            float w0 = (t == tp) ? 1.f : 0.f;
            float w1 = At[t * 8 + tp];
            float w2 = 0.f;
            #pragma unroll
            for (int kk = 0; kk < 8; ++kk) w2 += At[t * 8 + kk] * At[kk * 8 + tp];

            float a0, a1, a2, b0, b1, b2, d0, d1, d2;
            ctab(0 * 3 + bp, s0, s1, s2, s3, a0, a1, a2);
            ctab(1 * 3 + bp, s0, s1, s2, s3, b0, b1, b2);
            ctab(2 * 3 + bp, s0, s1, s2, s3, d0, d1, d2);
            float k0c = w0 * a0 + w1 * b0 + w2 * d0;
            float k1c = w0 * a1 + w1 * b1 + w2 * d1;
            float k2c = w0 * a2 + w1 * b2 + w2 * d2;

            float val = k0c * H[((size_t)(l * 3 + 0) * 64 + j) * 64 + f]
                      + k1c * H[((size_t)(l * 3 + 1) * 64 + j) * 64 + f]
                      + k2c * H[((size_t)(l * 3 + 2) * 64 + j) * 64 + f];
            GbigT[r] = (unsigned short)f2bf(val);
        }
    }
}

// ---------------------------------------------------------------------------
// prep2: Asqb = (As@As) bf16 [512][512]
// ---------------------------------------------------------------------------
__global__ __launch_bounds__(256) void prep2_k(const unsigned short* __restrict__ Asb,
                                               const unsigned short* __restrict__ AsbT,
                                               unsigned short* __restrict__ Asqb) {
    int tid = threadIdx.x;
    int wave = tid >> 6, lane = tid & 63;
    int l16 = lane & 15, quad = lane >> 4;
    int st = blockIdx.x, ct = blockIdx.y;

    const unsigned short* ap = Asb + (size_t)(st * 16 + l16) * SP + quad * 8;
    const unsigned short* bp = AsbT + (size_t)(ct * 64 + wave * 16 + l16) * SP + quad * 8;
    floatx4 acc = {};
    #pragma unroll 4
    for (int k0 = 0; k0 < SP; k0 += 32)
        acc = __builtin_amdgcn_mfma_f32_16x16x32_bf16(*(const bf16x8*)(ap + k0),
                                                      *(const bf16x8*)(bp + k0), acc, 0, 0, 0);
    int j = ct * 64 + wave * 16 + l16;
    int i0 = st * 16 + quad * 4;
    #pragma unroll
    for (int r = 0; r < 4; ++r)
        Asqb[(size_t)(i0 + r) * SP + j] = (unsigned short)f2bf(acc[r]);
}

// ---------------------------------------------------------------------------
// smm: dual LDS-tiled GEMM. u1 = As.xf, u2 = As^2.xf -> Abig slots b'=1,2.
// grid (8 m-tiles, 64 bt). Block tile 64s x 64f, K=512.
// ---------------------------------------------------------------------------
__global__ __launch_bounds__(256) void smm_k(const unsigned short* __restrict__ Asb,
                                             const unsigned short* __restrict__ Asqb,
                                             const unsigned short* __restrict__ xfT,
                                             unsigned short* __restrict__ Abig) {
    __shared__ unsigned short A1[64 * LROW];
    __shared__ unsigned short A2[64 * LROW];
    __shared__ unsigned short Bt[64 * LROW];

    int tid = threadIdx.x;
    int wave = tid >> 6, lane = tid & 63;
    int l16 = lane & 15, quad = lane >> 4;
    int m0 = blockIdx.x * 64, bt = blockIdx.y;
    int b = bt >> 3, t = bt & 7;

    const unsigned short* a1g = Asb + (size_t)m0 * SP;
    const unsigned short* a2g = Asqb + (size_t)m0 * SP;
    const unsigned short* bg  = xfT + (size_t)bt * FF * SP;

    floatx4 acc1[4] = {}, acc2[4] = {};

    for (int k0 = 0; k0 < SP; k0 += 64) {
        __syncthreads();
        #pragma unroll
        for (int it = 0; it < 2; ++it) {
            int idx = it * 256 + tid;
            int row = idx >> 3, c = idx & 7;
            int4 v1 = *(const int4*)(a1g + (size_t)row * SP + k0 + c * 8);
            int4 v2 = *(const int4*)(a2g + (size_t)row * SP + k0 + c * 8);
            int4 vb = *(const int4*)(bg  + (size_t)row * SP + k0 + c * 8);
            *(int4*)&A1[row * LROW + c * 8] = v1;
            *(int4*)&A2[row * LROW + c * 8] = v2;
            *(int4*)&Bt[row * LROW + c * 8] = vb;
        }
        __syncthreads();
        #pragma unroll
        for (int ks = 0; ks < 2; ++ks) {
            bf16x8 af1 = *(const bf16x8*)&A1[(wave * 16 + l16) * LROW + ks * 32 + quad * 8];
            bf16x8 af2 = *(const bf16x8*)&A2[(wave * 16 + l16) * LROW + ks * 32 + quad * 8];
            #pragma unroll
            for (int nt = 0; nt < 4; ++nt) {
                bf16x8 bf = *(const bf16x8*)&Bt[(nt * 16 + l16) * LROW + ks * 32 + quad * 8];
                acc1[nt] = __builtin_amdgcn_mfma_f32_16x16x32_bf16(af1, bf, acc1[nt], 0, 0, 0);
                acc2[nt] = __builtin_amdgcn_mfma_f32_16x16x32_bf16(af2, bf, acc2[nt], 0, 0, 0);
            }
        }
    }

    // epilogue: repack to row-major via LDS, write Abig slots 1 and 2
    __syncthreads();
    #pragma unroll
    for (int nt = 0; nt < 4; ++nt)
        #pragma unroll
        for (int r = 0; r < 4; ++r) {
            A1[(wave * 16 + quad * 4 + r) * LROW + nt * 16 + l16] = (unsigned short)f2bf(acc1[nt][r]);
            A2[(wave * 16 + quad * 4 + r) * LROW + nt * 16 + l16] = (unsigned short)f2bf(acc2[nt][r]);
        }
    __syncthreads();
    int row = wave * 16 + (lane >> 2);
    int c2 = (lane & 3) * 2;
    #pragma unroll
    for (int q = 0; q < 2; ++q) {
        int c = c2 + q;
        int4 v1 = *(const int4*)&A1[row * LROW + c * 8];
        int4 v2 = *(const int4*)&A2[row * LROW + c * 8];
        size_t base = (size_t)(b * SP + m0 + row) * KT + t * 192;
        *(int4*)(Abig + base + 64 + c * 8)  = v1;
        *(int4*)(Abig + base + 128 + c * 8) = v2;
    }
}

// ---------------------------------------------------------------------------
// tmix: C[(b,s)][(t,f)] = tanh( Abig[4096 x 1536] @ GbigT_l^T ), per-t n-tiles.
// grid (64 m-tiles, 8 t). Writes xfT_next and Abig_next slot0.
// ---------------------------------------------------------------------------
__global__ __launch_bounds__(256) void tmix_k(const unsigned short* __restrict__ Abig,
                                              const unsigned short* __restrict__ GbigT_l,
                                              unsigned short* __restrict__ xfT_out,
                                              unsigned short* __restrict__ Abig_out) {
    __shared__ unsigned short At_[64 * LROW];
    __shared__ unsigned short Bt_[64 * LROW];

    int tid = threadIdx.x;
    int wave = tid >> 6, lane = tid & 63;
    int l16 = lane & 15, quad = lane >> 4;
    int m0 = blockIdx.x * 64, t = blockIdx.y;
    int b = m0 >> 9, s0 = m0 & 511;

    const unsigned short* ag = Abig + (size_t)m0 * KT;
    const unsigned short* bg = GbigT_l + (size_t)t * FF * KT;

    floatx4 acc[4] = {};

    for (int kk = 0; kk < 24; ++kk) {
        __syncthreads();
        #pragma unroll
        for (int it = 0; it < 2; ++it) {
            int idx = it * 256 + tid;
            int row = idx >> 3, c = idx & 7;
            int4 va = *(const int4*)(ag + (size_t)row * KT + kk * 64 + c * 8);
            int4 vb = *(const int4*)(bg + (size_t)row * KT + kk * 64 + c * 8);
            *(int4*)&At_[row * LROW + c * 8] = va;
            *(int4*)&Bt_[row * LROW + c * 8] = vb;
        }
        __syncthreads();
        #pragma unroll
        for (int ks = 0; ks < 2; ++ks) {
            bf16x8 af = *(const bf16x8*)&At_[(wave * 16 + l16) * LROW + ks * 32 + quad * 8];
            #pragma unroll
            for (int nt = 0; nt < 4; ++nt) {
                bf16x8 bf = *(const bf16x8*)&Bt_[(nt * 16 + l16) * LROW + ks * 32 + quad * 8];
                acc[nt] = __builtin_amdgcn_mfma_f32_16x16x32_bf16(af, bf, acc[nt], 0, 0, 0);
            }
        }
    }

    // tanh
    #pragma unroll
    for (int nt = 0; nt < 4; ++nt)
        #pragma unroll
        for (int r = 0; r < 4; ++r) acc[nt][r] = tanhf(acc[nt][r]);

    int bt = b * 8 + t;

    // xfT write straight from registers: lane holds 4 consecutive s, fixed f
    {
        int sbase = s0 + wave * 16 + quad * 4;
        #pragma unroll
        for (int nt = 0; nt < 4; ++nt) {
            int f = nt * 16 + l16;
            int2 w;
            w.x = (int)(f2bf(acc[nt][0]) | (f2bf(acc[nt][1]) << 16));
            w.y = (int)(f2bf(acc[nt][2]) | (f2bf(acc[nt][3]) << 16));
            *(int2*)(xfT_out + ((size_t)bt * FF + f) * SP + sbase) = w;
        }
    }

    // Abig_out slot0 via LDS repack (coalesced int4 rows)
    __syncthreads();
    #pragma unroll
    for (int nt = 0; nt < 4; ++nt)
        #pragma unroll
        for (int r = 0; r < 4; ++r)
            At_[(wave * 16 + quad * 4 + r) * LROW + nt * 16 + l16] = (unsigned short)f2bf(acc[nt][r]);
    __syncthreads();
    {
        int row = wave * 16 + (lane >> 2);
        int c2 = (lane & 3) * 2;
        #pragma unroll
        for (int q = 0; q < 2; ++q) {
            int c = c2 + q;
            int4 v = *(const int4*)&At_[row * LROW + c * 8];
            *(int4*)(Abig_out + (size_t)(m0 + row) * KT + t * 192 + c * 8) = v;
        }
    }
}

// ---------------------------------------------------------------------------
// zredlin2: out[b,s,f] = b2[f]*sum(m) + sum_j (sum_t m[t] xf[b,t,s,j]) * W2[f,j]
// xf read from Abig slot0. grid (32 s-tiles of 16, 8 b)
// ---------------------------------------------------------------------------
__global__ __launch_bounds__(256) void zredlin2_k(const unsigned short* __restrict__ Abig,
                                                  const float* __restrict__ W2,
                                                  const float* __restrict__ b2,
                                                  const float* __restrict__ merge,
                                                  float* __restrict__ out) {
    __shared__ float Wl[FF][FF + 1];
    __shared__ float zt[16][FF + 1];
    __shared__ float ml[TT];
    int tid = threadIdx.x;
    int b = blockIdx.y, s0 = blockIdx.x * 16;

    for (int i = tid; i < FF * FF; i += 256) { int f = i >> 6, j = i & 63; Wl[j][f] = W2[i]; }
    if (tid < TT) ml[tid] = merge[tid];
    __syncthreads();

    float m[TT];
    #pragma unroll
    for (int t = 0; t < TT; ++t) m[t] = ml[t];
    float msum = 0.f;
    #pragma unroll
    for (int t = 0; t < TT; ++t) msum += m[t];

    #pragma unroll
    for (int p = 0; p < 4; ++p) {
        int lin = p * 256 + tid;
        int sl = lin >> 6, f = lin & 63;
        int s = s0 + sl;
        float acc = 0.f;
        if (s < SS) {
            #pragma unroll
            for (int t = 0; t < TT; ++t)
                acc += m[t] * bf2f(Abig[(size_t)(b * SP + s) * KT + t * 192 + f]);
        }
        zt[sl][f] = acc;
    }
    __syncthreads();

    int f = tid & 63, sq = tid >> 6;
    #pragma unroll
    for (int i = 0; i < 4; ++i) {
        int sl = sq * 4 + i;
        int s = s0 + sl;
        if (s < SS) {
            float acc = b2[f] * msum;
            #pragma unroll
            for (int j = 0; j < FF; ++j) acc += zt[sl][j] * Wl[j][f];
            out[((size_t)b * SS + s) * FF + f] = acc;
        }
    }
}

// ---------------------------------------------------------------------------
extern "C" void kernel_launch(void* const* d_in, const int* in_sizes, int n_in,
                              void* d_out, int out_size, void* d_ws, size_t ws_size,
                              hipStream_t stream) {
    const float* x     = (const float*)d_in[0];
    const float* At    = (const float*)d_in[1];
    const float* As    = (const float*)d_in[2];
    const float* sc    = (const float*)d_in[3];
    const float* H     = (const float*)d_in[4];
    const float* W1    = (const float*)d_in[5];
    const float* b1    = (const float*)d_in[6];
    const float* W2    = (const float*)d_in[7];
    const float* b2    = (const float*)d_in[8];
    const float* merge = (const float*)d_in[9];
    float* out = (float*)d_out;

    char* ws = (char*)d_ws;
    unsigned short* Asb   = (unsigned short*)(ws + 0);          // 524288
    unsigned short* AsbT  = (unsigned short*)(ws + 524288);     // 524288
    unsigned short* Asqb  = (unsigned short*)(ws + 1048576);    // 524288
    unsigned short* GbigT = (unsigned short*)(ws + 1572864);    // 4718592
    unsigned short* xfT0  = (unsigned short*)(ws + 6291456);    // 4194304
    unsigned short* xfT1  = (unsigned short*)(ws + 10485760);   // 4194304
    unsigned short* Abig0 = (unsigned short*)(ws + 14680064);   // 12582912
    unsigned short* Abig1 = (unsigned short*)(ws + 27262976);   // 12582912

    setup_k<<<11776, 256, 0, stream>>>(x, W1, b1, As, At, sc, H,
                                       Asb, AsbT, GbigT, xfT0, Abig0);
    prep2_k<<<dim3(32, 8), 256, 0, stream>>>(Asb, AsbT, Asqb);

    unsigned short* xfT_cur = xfT0;  unsigned short* xfT_nxt = xfT1;
    unsigned short* Abig_cur = Abig0; unsigned short* Abig_nxt = Abig1;
    for (int l = 0; l < 3; ++l) {
        smm_k<<<dim3(8, NBT), 256, 0, stream>>>(Asb, Asqb, xfT_cur, Abig_cur);
        tmix_k<<<dim3(64, 8), 256, 0, stream>>>(Abig_cur,
                                                GbigT + (size_t)l * 8 * FF * KT,
                                                xfT_nxt, Abig_nxt);
        unsigned short* tt = xfT_cur;  xfT_cur = xfT_nxt;  xfT_nxt = tt;
        unsigned short* tb = Abig_cur; Abig_cur = Abig_nxt; Abig_nxt = tb;
    }
    zredlin2_k<<<dim3(32, 8), 256, 0, stream>>>(Abig_cur, W2, b2, merge, out);
}